// Round 1
// 226.799 us; speedup vs baseline: 1.0539x; 1.0539x over previous
//
#include <hip/hip_runtime.h>
#include <cstdint>
#include <cstddef>

#define NPIX (512 * 512)
#define NMAPS 64
#define NPTS 300
#define CAP 2048           // per-map candidate region (32 blocks x 64 slots)
#define SLOTS 64           // per-block candidate slots (E~19, 10 sigma safe)
#define LBUFSZ 256         // LDS staging for per-block survivors
#define NWORDS 4096        // 262144 bits / 64
#define TARGET 700.0       // fallback rescan target
// Fixed keep-rate 20000/2^23: E~620 survivors/map (N~260K measured r10).
// Compare raw threefry bits against MT<<9 (exactly equiv to score>=MT).
#define MT_BITS 0xFF63C000u  // (8388608-20000)<<9

__device__ __forceinline__ uint32_t umin32(uint32_t a, uint32_t b) {
  return a < b ? a : b;
}

// ---------------------------------------------------------------------------
// Threefry-2x32, 20 rounds (exactly JAX's formulation).
// ---------------------------------------------------------------------------
__device__ __forceinline__ void tf2x32(uint32_t k0, uint32_t k1,
                                       uint32_t x0, uint32_t x1,
                                       uint32_t& o0, uint32_t& o1) {
  uint32_t ks2 = k0 ^ k1 ^ 0x1BD11BDAu;
#define TFR(r) { x0 += x1; x1 = (x1 << (r)) | (x1 >> (32 - (r))); x1 ^= x0; }
  x0 += k0; x1 += k1;
  TFR(13) TFR(15) TFR(26) TFR(6)
  x0 += k1; x1 += ks2 + 1u;
  TFR(17) TFR(29) TFR(16) TFR(24)
  x0 += ks2; x1 += k0 + 2u;
  TFR(13) TFR(15) TFR(26) TFR(6)
  x0 += k0; x1 += k1 + 3u;
  TFR(17) TFR(29) TFR(16) TFR(24)
  x0 += k1; x1 += ks2 + 4u;
  TFR(13) TFR(15) TFR(26) TFR(6)
  x0 += ks2; x1 += k0 + 5u;
#undef TFR
  o0 = x0; o1 = x1;
}

__device__ __forceinline__ uint32_t score23(uint32_t k0, uint32_t k1, uint32_t p) {
  uint32_t a, b;
  tf2x32(k0, k1, 0u, p, a, b);
  return (a ^ b) >> 9;
}

__device__ __forceinline__ void map_key(int m, uint32_t& k0, uint32_t& k1) {
  tf2x32(0u, 42u, 0u, (uint32_t)m, k0, k1);  // split(key(42),64)[m]
}

// DPP helper (validated ctrl constants; CTRL must be an ICE -> template).
template <int CTRL>
__device__ __forceinline__ uint32_t dpp_mov_u32(uint32_t x) {
  return (uint32_t)__builtin_amdgcn_update_dpp((int)x, (int)x, CTRL, 0xF, 0xF,
                                               false);
}

// DPP with old=0: invalid source lanes contribute 0 (for OR-reduce).
template <int CTRL>
__device__ __forceinline__ uint32_t dpp_or0(uint32_t x) {
  return (uint32_t)__builtin_amdgcn_update_dpp(0, (int)x, CTRL, 0xF, 0xF,
                                               false);
}

// wave-64 u32 min reduction (HW-validated, absmax 0 across rounds).
__device__ __forceinline__ uint32_t wave_min_u32_bcast(uint32_t v) {
  v = umin32(v, dpp_mov_u32<0x111>(v));  // row_shr:1
  v = umin32(v, dpp_mov_u32<0x112>(v));  // row_shr:2
  v = umin32(v, dpp_mov_u32<0x114>(v));  // row_shr:4
  v = umin32(v, dpp_mov_u32<0x118>(v));  // row_shr:8
  v = umin32(v, dpp_mov_u32<0x142>(v));  // row_bcast:15
  v = umin32(v, dpp_mov_u32<0x143>(v));  // row_bcast:31
  return (uint32_t)__builtin_amdgcn_readlane((int)v, 63);
}

// ---------------------------------------------------------------------------
// K1 body: 4 contiguous columns per lane via float4 loads. Wave covers
// 256 cols x 8 rows. Shuffles (2 per t/u pair) amortize over 4 px; the
// bitmap word (same y*8+cs layout) is assembled from per-lane nibbles via
// a 4-step DPP row_shr OR-reduce within each 16-lane group. 4 independent
// threefry chains per lane per row give 4x ILP on the dominant chain.
// Explicit next-row prefetch hides vmem latency under the threefry work.
// ---------------------------------------------------------------------------
template <bool PRED, bool YIN>
__device__ __forceinline__ float4 ld4row(const float* __restrict__ src,
                                         int row, int X0) {
  if constexpr (!YIN) {
    if ((unsigned)row >= 512u) return make_float4(0.f, 0.f, 0.f, 0.f);
  }
  float4 v = *reinterpret_cast<const float4*>(src + (size_t)row * 512 + X0);
  if constexpr (PRED) {
    v.x = 1.f / (1.f + __expf(-v.x));
    v.y = 1.f / (1.f + __expf(-v.y));
    v.z = 1.f / (1.f + __expf(-v.z));
    v.w = 1.f / (1.f + __expf(-v.w));
  }
  return v;
}

template <bool PRED, bool YIN>
__device__ __forceinline__ float ldhrow(const float* __restrict__ src,
                                        int row, int hx, bool hact) {
  if (!hact) return 0.f;  // non-halo lanes: raw 0 (zero-pad semantics)
  if constexpr (!YIN) {
    if ((unsigned)row >= 512u) return 0.f;
  }
  float t = src[(size_t)row * 512 + hx];
  if constexpr (PRED) t = 1.f / (1.f + __expf(-t));
  return t;
}

__device__ __forceinline__ void push_surv(unsigned long long* lbuf,
                                          unsigned int* lcnt, uint32_t x,
                                          uint32_t p) {
  unsigned int pos = atomicAdd(lcnt, 1u);
  if (pos < LBUFSZ)
    lbuf[pos] = ((unsigned long long)(x >> 9) << 32) | (uint32_t)(~p);
}

template <bool PRED, bool YIN>
__device__ __forceinline__ void edge_body(
    const float* __restrict__ src, unsigned long long* __restrict__ bitmap,
    unsigned int* __restrict__ wcnts, unsigned long long* lbuf,
    unsigned int* lcnt, int m, int l, int h, int r, int wi, uint32_t k0,
    uint32_t k1) {
  const int y0 = r * 8;
  const int X0 = h * 256 + l * 4;      // lane's first column (absolute)
  const int hx = 256 - h;              // halo col: 256 (h=0) / 255 (h=1)
  const bool hact = h ? (l == 0) : (l == 63);
  const int lr = l & 15;

  float4 a = ld4row<PRED, YIN>(src, y0 - 1, X0);
  float4 b = ld4row<PRED, YIN>(src, y0, X0);
  float ha = ldhrow<PRED, YIN>(src, y0 - 1, hx, hact);
  float hb = ldhrow<PRED, YIN>(src, y0, hx, hact);
  float4 cn = ld4row<PRED, YIN>(src, y0 + 1, X0);  // prefetched row
  float hcn = ldhrow<PRED, YIN>(src, y0 + 1, hx, hact);

  unsigned int cnt = 0;
  // word index within row: h*4 + (l>>4); only lanes with lr==15 store.
  unsigned long long* __restrict__ bm =
      bitmap + (size_t)m * NWORDS + (h * 4 + (l >> 4));

#pragma unroll 2
  for (int i = 0; i < 8; ++i) {
    const int y = y0 + i;
    float4 c = cn;
    float hc = hcn;
    if (i < 7) {  // issue next row's loads before the heavy compute
      cn = ld4row<PRED, YIN>(src, y + 2, X0);
      hcn = ldhrow<PRED, YIN>(src, y + 2, hx, hact);
    }

    float t0 = a.x + 2.f * b.x + c.x, t1 = a.y + 2.f * b.y + c.y;
    float t2 = a.z + 2.f * b.z + c.z, t3 = a.w + 2.f * b.w + c.w;
    float u0 = c.x - a.x, u1 = c.y - a.y, u2 = c.z - a.z, u3 = c.w - a.w;
    float th = ha + 2.f * hb + hc, uh = hc - ha;

    float tU = __shfl_up(t3, 1), uU = __shfl_up(u3, 1);
    float tD = __shfl_down(t0, 1), uD = __shfl_down(u0, 1);
    if (l == 0) { tU = th; uU = uh; }    // h=1: real col 255; h=0: 0 (pad)
    if (l == 63) { tD = th; uD = uh; }   // h=0: real col 256; h=1: 0 (pad)

    float ex0 = t1 - tU, ex1 = t2 - t0, ex2 = t3 - t1, ex3 = tD - t2;
    float ey0 = uU + 2.f * u0 + u1, ey1 = u0 + 2.f * u1 + u2;
    float ey2 = u1 + 2.f * u2 + u3, ey3 = u2 + 2.f * u3 + uD;

    bool b0 = ex0 * ex0 + ey0 * ey0 > 0.25f;
    bool b1 = ex1 * ex1 + ey1 * ey1 > 0.25f;
    bool b2 = ex2 * ex2 + ey2 * ey2 > 0.25f;
    bool b3 = ex3 * ex3 + ey3 * ey3 > 0.25f;

    // 4 independent threefry chains (unconditional: ~85% density anyway).
    const uint32_t pb = (uint32_t)(y * 512 + X0);
    uint32_t q0, q1, q2, q3;
    { uint32_t o0, o1; tf2x32(k0, k1, 0u, pb + 0u, o0, o1); q0 = o0 ^ o1; }
    { uint32_t o0, o1; tf2x32(k0, k1, 0u, pb + 1u, o0, o1); q1 = o0 ^ o1; }
    { uint32_t o0, o1; tf2x32(k0, k1, 0u, pb + 2u, o0, o1); q2 = o0 ^ o1; }
    { uint32_t o0, o1; tf2x32(k0, k1, 0u, pb + 3u, o0, o1); q3 = o0 ^ o1; }

    if (b0 && q0 >= MT_BITS) push_surv(lbuf, lcnt, q0, pb + 0u);
    if (b1 && q1 >= MT_BITS) push_surv(lbuf, lcnt, q1, pb + 1u);
    if (b2 && q2 >= MT_BITS) push_surv(lbuf, lcnt, q2, pb + 2u);
    if (b3 && q3 >= MT_BITS) push_surv(lbuf, lcnt, q3, pb + 3u);

    // bitmap word assembly: nibble at bit 4*lr, OR-reduce over 16 lanes.
    uint32_t nib = (b0 ? 1u : 0u) | (b1 ? 2u : 0u) | (b2 ? 4u : 0u) |
                   (b3 ? 8u : 0u);
    unsigned long long full = (unsigned long long)nib << (4 * lr);
    uint32_t wlo = (uint32_t)full, whi = (uint32_t)(full >> 32);
    wlo |= dpp_or0<0x111>(wlo); whi |= dpp_or0<0x111>(whi);  // row_shr:1
    wlo |= dpp_or0<0x112>(wlo); whi |= dpp_or0<0x112>(whi);  // row_shr:2
    wlo |= dpp_or0<0x114>(wlo); whi |= dpp_or0<0x114>(whi);  // row_shr:4
    wlo |= dpp_or0<0x118>(wlo); whi |= dpp_or0<0x118>(whi);  // row_shr:8
    if (lr == 15) {  // lanes 15/31/47/63 hold the 4 full words
      unsigned long long word = ((unsigned long long)whi << 32) | wlo;
      bm[(size_t)y * 8] = word;
      cnt += (unsigned int)__popcll(word);
    }

    a = b; b = c; ha = hb; hb = hc;
  }

  // wave total = sum of the 4 tail-lane partials.
  cnt += __shfl_xor(cnt, 16);
  cnt += __shfl_xor(cnt, 32);
  if (l == 15) wcnts[m * 128 + wi] = cnt;
}

// ---------------------------------------------------------------------------
// K1: fused Sobel+threefry+collect. Per-BLOCK candidate slots (no global
// atomics, no memset). Block bx covers rows [16bx,16bx+16) x all 512 cols
// = 8192 px (same per-block survivor stats as before -> SLOTS unchanged).
// wi in [0,128): h = wi&1 (col half), r = wi>>1 (8-row strip).
// ---------------------------------------------------------------------------
__global__ __launch_bounds__(256) void edge_collect_kernel(
    const float* __restrict__ mo, const float* __restrict__ lb,
    unsigned long long* __restrict__ bitmap, unsigned int* __restrict__ wcnts,
    unsigned long long* __restrict__ cand, unsigned int* __restrict__ bcnt,
    float* __restrict__ out) {
  const int m = blockIdx.y;
  const int which = m & 1;
  const int bx = blockIdx.x;
  const float* __restrict__ src = (which ? lb : mo) + (size_t)(m >> 1) * NPIX;
  const int l = threadIdx.x & 63;
  const int wi = bx * 4 + (threadIdx.x >> 6);  // [0,128)
  const int h = wi & 1;
  const int r = wi >> 1;  // [0,64): 8-row strip index

  if (m == 0 && bx == 0 && threadIdx.x == 0) out[0] = 0.f;

  __shared__ unsigned long long lbuf[LBUFSZ];
  __shared__ unsigned int lcnt;
  if (threadIdx.x == 0) lcnt = 0;
  __syncthreads();

  uint32_t k0, k1;
  map_key(m, k0, k1);
  k0 = (uint32_t)__builtin_amdgcn_readfirstlane((int)k0);  // uniform -> SGPR
  k1 = (uint32_t)__builtin_amdgcn_readfirstlane((int)k1);

  const bool yin = (r != 0) && (r != 63);
  if (which) {
    if (yin) edge_body<false, true>(src, bitmap, wcnts, lbuf, &lcnt, m, l, h, r, wi, k0, k1);
    else     edge_body<false, false>(src, bitmap, wcnts, lbuf, &lcnt, m, l, h, r, wi, k0, k1);
  } else {
    if (yin) edge_body<true, true>(src, bitmap, wcnts, lbuf, &lcnt, m, l, h, r, wi, k0, k1);
    else     edge_body<true, false>(src, bitmap, wcnts, lbuf, &lcnt, m, l, h, r, wi, k0, k1);
  }

  __syncthreads();
  const unsigned int total = lcnt;
  const unsigned int cc = total < SLOTS ? total : SLOTS;
  for (unsigned int i = threadIdx.x; i < cc; i += 256)
    cand[(size_t)m * CAP + bx * SLOTS + i] = lbuf[i];
  if (threadIdx.x == 0) bcnt[m * 32 + bx] = total;
}

// block-level N = sum of the 128 per-wave counts.
__device__ __forceinline__ void reduce_N(const unsigned int* __restrict__ wcnts,
                                         int m, int tid, unsigned int* sN) {
  if (tid < 64) {
    unsigned int v = wcnts[m * 128 + tid] + wcnts[m * 128 + 64 + tid];
#pragma unroll
    for (int off = 32; off > 0; off >>= 1) v += __shfl_xor(v, off, 64);
    if (tid == 0) *sN = v;
  }
}

// ---------------------------------------------------------------------------
// K2: compact per-block slots -> radix-SELECT top-`need` set. Fallback exact
// bitmap rescan on overflow/shortfall (correctness unconditional).
// ---------------------------------------------------------------------------
__global__ __launch_bounds__(256) void select_kernel(
    const unsigned long long* __restrict__ bitmap,
    const unsigned int* __restrict__ wcnts,
    const unsigned long long* __restrict__ cand,
    const unsigned int* __restrict__ bcnt,
    uint32_t* __restrict__ pts, unsigned int* __restrict__ nsel) {
  const int m = blockIdx.x;
  const int tid = threadIdx.x;
  __shared__ unsigned long long buf[CAP];
  __shared__ unsigned int hist[256];
  __shared__ unsigned int scnt32[32];
  __shared__ unsigned int sbase[33];
  __shared__ unsigned int s_tot, s_cnt, s_b, s_rank, sN, s_ovf;

  reduce_N(wcnts, m, tid, &sN);
  if (tid < 32) scnt32[tid] = bcnt[m * 32 + tid];
  __syncthreads();
  const unsigned int N = sN;
  if (N == 0) { if (tid == 0) nsel[m] = 0; return; }
  const unsigned int need = N < NPTS ? N : NPTS;

  if (tid == 0) {
    unsigned int s = 0, ovf = 0;
    for (int i = 0; i < 32; ++i) {
      sbase[i] = s;
      unsigned int cg = scnt32[i];
      if (cg > SLOTS) ovf = 1;
      s += cg < SLOTS ? cg : SLOTS;
    }
    sbase[32] = s;
    s_ovf = ovf;
  }
  __syncthreads();

  unsigned int c;
  if (!s_ovf && sbase[32] >= need) {
    c = sbase[32];
    const int g = tid >> 3, j0 = tid & 7;  // 32 groups x 8 threads
    const unsigned int cg = scnt32[g] < SLOTS ? scnt32[g] : SLOTS;
    for (unsigned int i = j0; i < cg; i += 8)
      buf[sbase[g] + i] = cand[(size_t)m * CAP + g * SLOTS + i];
    __syncthreads();
  } else {
    // fallback: exact iterative rescan of the bitmap
    uint32_t k0, k1;
    map_key(m, k0, k1);
    const unsigned long long* __restrict__ wmap = bitmap + (size_t)m * NWORDS;
    unsigned int mt = 0, cnt = 0;
    double target = TARGET;
    for (int iter = 0; iter < 16; ++iter) {
      mt = ((double)N > target)
               ? (unsigned int)(8388608.0 * (1.0 - target / (double)N))
               : 0u;
      if (tid == 0) s_tot = 0;
      __syncthreads();
      unsigned int lc = 0;
      for (int w = tid; w < NWORDS; w += 256) {
        unsigned long long word = wmap[w];
        while (word) {
          int bpos = __builtin_ctzll(word);
          word &= word - 1;
          uint32_t p = ((uint32_t)w << 6) + (uint32_t)bpos;
          lc += (score23(k0, k1, p) >= mt) ? 1u : 0u;
        }
      }
      if (lc) atomicAdd(&s_tot, lc);
      __syncthreads();
      cnt = s_tot;
      __syncthreads();
      if (cnt >= need && cnt <= CAP) break;
      if (cnt < need) target *= 3.0; else target *= 0.5;
    }
    if (tid == 0) s_cnt = 0;
    __syncthreads();
    for (int w = tid; w < NWORDS; w += 256) {
      unsigned long long word = wmap[w];
      while (word) {
        int bpos = __builtin_ctzll(word);
        word &= word - 1;
        uint32_t p = ((uint32_t)w << 6) + (uint32_t)bpos;
        uint32_t sc = score23(k0, k1, p);
        if (sc >= mt) {
          unsigned int pos = atomicAdd(&s_cnt, 1u);
          if (pos < CAP)
            buf[pos] = ((unsigned long long)sc << 32) | (uint32_t)(~p);
        }
      }
    }
    __syncthreads();
    c = s_cnt < CAP ? s_cnt : CAP;
    __syncthreads();
  }

  unsigned long long T = 0ull;
  if (c > need) {
    unsigned int rank = need;
    unsigned long long prefix = 0ull;
    for (int sh = 48; sh >= 0; sh -= 8) {
      hist[tid] = 0;
      __syncthreads();
      for (unsigned int i = tid; i < c; i += 256) {
        unsigned long long k = buf[i];
        if ((k >> (sh + 8)) == (prefix >> (sh + 8)))
          atomicAdd(&hist[(unsigned int)(k >> sh) & 255u], 1u);
      }
      __syncthreads();
      if (tid < 64) {
        unsigned int h0 = hist[4 * tid], h1 = hist[4 * tid + 1];
        unsigned int h2 = hist[4 * tid + 2], h3 = hist[4 * tid + 3];
        unsigned int gsum = h0 + h1 + h2 + h3;
        unsigned int s = gsum;
#pragma unroll
        for (int off = 1; off < 64; off <<= 1) {
          unsigned int o = __shfl_down(s, off, 64);
          s += (tid + off < 64) ? o : 0u;
        }
        unsigned int above = s - gsum;  // strictly higher digits
        unsigned int S3 = above, S2 = S3 + h3, S1 = S2 + h2, S0 = S1 + h1;
        if (S3 < rank && rank <= S3 + h3) { s_b = 4 * tid + 3; s_rank = rank - S3; }
        if (S2 < rank && rank <= S2 + h2) { s_b = 4 * tid + 2; s_rank = rank - S2; }
        if (S1 < rank && rank <= S1 + h1) { s_b = 4 * tid + 1; s_rank = rank - S1; }
        if (S0 < rank && rank <= S0 + h0) { s_b = 4 * tid + 0; s_rank = rank - S0; }
      }
      __syncthreads();
      prefix |= ((unsigned long long)s_b) << sh;
      rank = s_rank;
    }
    T = prefix;  // exact need-th largest key
  }

  if (tid == 0) s_cnt = 0;
  __syncthreads();
  for (unsigned int i = tid; i < c; i += 256) {
    unsigned long long k = buf[i];
    if (k >= T) {
      unsigned int pos = atomicAdd(&s_cnt, 1u);
      if (pos < NPTS) {
        uint32_t p = ~(uint32_t)k;
        pts[(size_t)m * NPTS + pos] = ((p >> 9) << 16) | (p & 511u);
      }
    }
  }
  __syncthreads();
  if (tid == 0) nsel[m] = s_cnt < need ? s_cnt : need;
}

// ---------------------------------------------------------------------------
// K3: Prim MST + fused finalize (unchanged — passed absmax 0).
// ---------------------------------------------------------------------------
__global__ __launch_bounds__(128, 1) void mst_kernel(
    const uint32_t* __restrict__ pts, const unsigned int* __restrict__ nsel,
    float* __restrict__ out) {
  const int wv = threadIdx.x >> 6;  // 0 = pred, 1 = mask
  const int m = blockIdx.x * 2 + wv;
  const int l = threadIdx.x & 63;
  const int n = (int)nsel[m];
  __shared__ float stp[2];

  unsigned int utp = 0;
  if (n > 1) {
    uint32_t pk[5], key[5];
    int px[5], py[5];
#pragma unroll
    for (int k = 0; k < 5; ++k) {
      int id = k * 64 + l;
      pk[k] = (id < n) ? pts[(size_t)m * NPTS + id] : 0u;
    }
    const uint32_t p0 = (uint32_t)__builtin_amdgcn_readlane((int)pk[0], 0);
    const int x0 = (int)(p0 >> 16), y0 = (int)(p0 & 0xFFFFu);
#pragma unroll
    for (int k = 0; k < 5; ++k) {
      int id = k * 64 + l;
      px[k] = (int)(pk[k] >> 16);
      py[k] = (int)(pk[k] & 0xFFFFu);
      if (id > 0 && id < n) {
        int dx = px[k] - x0, dy = py[k] - y0;
        key[k] = ((uint32_t)(__mul24(dx, dx) + __mul24(dy, dy)) << 9) |
                 (uint32_t)id;
      } else {
        key[k] = 0xFFFFFFFFu;
      }
    }

    for (int it = 0; it < n - 1; ++it) {
      uint32_t best = umin32(umin32(umin32(key[0], key[1]),
                                    umin32(key[2], key[3])), key[4]);
      best = wave_min_u32_bcast(best);
      utp += best >> 9;  // exact: sum < 2^31
      const int j = (int)(best & 511u);
      const int ko = j >> 6, lo = j & 63;
      uint32_t cp = pk[0];
#pragma unroll
      for (int k = 1; k < 5; ++k) cp = (ko == k) ? pk[k] : cp;
      const uint32_t pj = (uint32_t)__builtin_amdgcn_readlane((int)cp, lo);
      const int jx = (int)(pj >> 16), jy = (int)(pj & 0xFFFFu);
#pragma unroll
      for (int k = 0; k < 5; ++k) {
        int dx = px[k] - jx, dy = py[k] - jy;
        uint32_t nk = ((uint32_t)(__mul24(dx, dx) + __mul24(dy, dy)) << 9) |
                      (uint32_t)(k * 64 + l);
        uint32_t upd =
            (key[k] == 0xFFFFFFFFu) ? 0xFFFFFFFFu : umin32(key[k], nk);
        key[k] = (k == ko && l == lo) ? 0xFFFFFFFFu : upd;
      }
    }
  }
  if (l == 0) stp[wv] = (float)utp;
  __syncthreads();
  if (threadIdx.x == 0)
    atomicAdd(out, 1e-5f * fabsf(stp[1] - stp[0]) / 32.f);
}

// ---------------------------------------------------------------------------
extern "C" void kernel_launch(void* const* d_in, const int* in_sizes, int n_in,
                              void* d_out, int out_size, void* d_ws,
                              size_t ws_size, hipStream_t stream) {
  const float* mo = (const float*)d_in[0];
  const float* lb = (const float*)d_in[1];
  float* out = (float*)d_out;
  char* ws = (char*)d_ws;

  // ws layout (~3.26 MB):
  unsigned long long* bitmap = (unsigned long long*)ws;            // 2 MB
  unsigned long long* cand = (unsigned long long*)(ws + 2097152);  // 1 MB
  unsigned int* wcnts = (unsigned int*)(ws + 3145728);             // 32 KB
  unsigned int* bcnt  = (unsigned int*)(ws + 3178496);             // 8 KB
  unsigned int* nsel  = (unsigned int*)(ws + 3186688);             // 256 B
  uint32_t* pts       = (uint32_t*)(ws + 3186944);                 // 75 KB

  edge_collect_kernel<<<dim3(32, 64), 256, 0, stream>>>(mo, lb, bitmap, wcnts,
                                                        cand, bcnt, out);
  select_kernel<<<NMAPS, 256, 0, stream>>>(bitmap, wcnts, cand, bcnt, pts,
                                           nsel);
  mst_kernel<<<32, 128, 0, stream>>>(pts, nsel, out);
}

// Round 3
// 215.193 us; speedup vs baseline: 1.1107x; 1.0539x over previous
//
#include <hip/hip_runtime.h>
#include <cstdint>
#include <cstddef>

#define NPIX (512 * 512)
#define NMAPS 64
#define NPTS 300
#define CAP 2048           // per-map candidate region (64 bands x 32 slots)
#define SLOTS 32           // per-band-per-map candidate slots (E~9.7, 7 sigma)
#define LBUFSZ 64          // LDS staging per part
#define NWORDS 4096        // 262144 bits / 64
#define TARGET 700.0       // fallback rescan target
// Fixed keep-rate 20000/2^23: E~620 survivors/map.
// Compare raw threefry bits against MT<<9 (exactly equiv to score>=MT).
#define MT_BITS 0xFF63C000u  // (8388608-20000)<<9

__device__ __forceinline__ uint32_t umin32(uint32_t a, uint32_t b) {
  return a < b ? a : b;
}

// Portable rotate; r is always a compile-time constant in [6,29], clang
// lowers this to a single v_alignbit_b32 on gfx950.
__device__ __forceinline__ uint32_t rotl32(uint32_t x, int r) {
  return (x << r) | (x >> (32 - r));
}

// ---------------------------------------------------------------------------
// Threefry-2x32, 20 rounds (exactly JAX's formulation).
// Scalar version (K2 fallback + key derivation).
// ---------------------------------------------------------------------------
__device__ __forceinline__ void tf2x32(uint32_t k0, uint32_t k1,
                                       uint32_t x0, uint32_t x1,
                                       uint32_t& o0, uint32_t& o1) {
  uint32_t ks2 = k0 ^ k1 ^ 0x1BD11BDAu;
#define TFR(r) { x0 += x1; x1 = rotl32(x1, r); x1 ^= x0; }
  x0 += k0; x1 += k1;
  TFR(13) TFR(15) TFR(26) TFR(6)
  x0 += k1; x1 += ks2 + 1u;
  TFR(17) TFR(29) TFR(16) TFR(24)
  x0 += ks2; x1 += k0 + 2u;
  TFR(13) TFR(15) TFR(26) TFR(6)
  x0 += k0; x1 += k1 + 3u;
  TFR(17) TFR(29) TFR(16) TFR(24)
  x0 += k1; x1 += ks2 + 4u;
  TFR(13) TFR(15) TFR(26) TFR(6)
  x0 += ks2; x1 += k0 + 5u;
#undef TFR
  o0 = x0; o1 = x1;
}

// 4-pixel batched threefry: 4 manually interleaved chains (counter pb..pb+3).
// Guarantees 4-way ILP on the serial add->rotl->xor chain.
__device__ __forceinline__ void tf4(uint32_t k0, uint32_t k1, uint32_t pb,
                                    uint32_t& z0, uint32_t& z1, uint32_t& z2,
                                    uint32_t& z3) {
  const uint32_t ks2 = k0 ^ k1 ^ 0x1BD11BDAu;
  const uint32_t s = pb + k1;
  uint32_t a0 = k0, a1 = s;
  uint32_t b0 = k0, b1 = s + 1u;
  uint32_t c0 = k0, c1 = s + 2u;
  uint32_t d0 = k0, d1 = s + 3u;
#define R4(r)                                                         \
  a0 += a1; b0 += b1; c0 += c1; d0 += d1;                             \
  a1 = rotl32(a1, r); b1 = rotl32(b1, r);                             \
  c1 = rotl32(c1, r); d1 = rotl32(d1, r);                             \
  a1 ^= a0; b1 ^= b0; c1 ^= c0; d1 ^= d0;
#define K4(ka, kb)                                                    \
  a0 += (ka); b0 += (ka); c0 += (ka); d0 += (ka);                     \
  a1 += (kb); b1 += (kb); c1 += (kb); d1 += (kb);
  R4(13) R4(15) R4(26) R4(6)  K4(k1, ks2 + 1u)
  R4(17) R4(29) R4(16) R4(24) K4(ks2, k0 + 2u)
  R4(13) R4(15) R4(26) R4(6)  K4(k0, k1 + 3u)
  R4(17) R4(29) R4(16) R4(24) K4(k1, ks2 + 4u)
  R4(13) R4(15) R4(26) R4(6)  K4(ks2, k0 + 5u)
#undef R4
#undef K4
  z0 = a0 ^ a1; z1 = b0 ^ b1; z2 = c0 ^ c1; z3 = d0 ^ d1;
}

__device__ __forceinline__ uint32_t score23(uint32_t k0, uint32_t k1, uint32_t p) {
  uint32_t a, b;
  tf2x32(k0, k1, 0u, p, a, b);
  return (a ^ b) >> 9;
}

__device__ __forceinline__ void map_key(int m, uint32_t& k0, uint32_t& k1) {
  tf2x32(0u, 42u, 0u, (uint32_t)m, k0, k1);  // split(key(42),64)[m]
}

// DPP helper (validated ctrl constants; CTRL must be an ICE -> template).
template <int CTRL>
__device__ __forceinline__ uint32_t dpp_mov_u32(uint32_t x) {
  return (uint32_t)__builtin_amdgcn_update_dpp((int)x, (int)x, CTRL, 0xF, 0xF,
                                               false);
}

// DPP with old=0: invalid source lanes contribute 0 (for OR-reduce).
template <int CTRL>
__device__ __forceinline__ uint32_t dpp_or0(uint32_t x) {
  return (uint32_t)__builtin_amdgcn_update_dpp(0, (int)x, CTRL, 0xF, 0xF,
                                               false);
}

// wave-64 u32 min reduction (HW-validated, absmax 0 across rounds).
__device__ __forceinline__ uint32_t wave_min_u32_bcast(uint32_t v) {
  v = umin32(v, dpp_mov_u32<0x111>(v));  // row_shr:1
  v = umin32(v, dpp_mov_u32<0x112>(v));  // row_shr:2
  v = umin32(v, dpp_mov_u32<0x114>(v));  // row_shr:4
  v = umin32(v, dpp_mov_u32<0x118>(v));  // row_shr:8
  v = umin32(v, dpp_mov_u32<0x142>(v));  // row_bcast:15
  v = umin32(v, dpp_mov_u32<0x143>(v));  // row_bcast:31
  return (uint32_t)__builtin_amdgcn_readlane((int)v, 63);
}

// ---------------------------------------------------------------------------
// K1 loads: 4 contiguous columns per lane via float4; sigmoid at load.
// ---------------------------------------------------------------------------
template <bool PRED, bool YIN>
__device__ __forceinline__ float4 ld4row(const float* __restrict__ src,
                                         int row, int X0) {
  if constexpr (!YIN) {
    if ((unsigned)row >= 512u) return make_float4(0.f, 0.f, 0.f, 0.f);
  }
  float4 v = *reinterpret_cast<const float4*>(src + (size_t)row * 512 + X0);
  if constexpr (PRED) {
    v.x = 1.f / (1.f + __expf(-v.x));
    v.y = 1.f / (1.f + __expf(-v.y));
    v.z = 1.f / (1.f + __expf(-v.z));
    v.w = 1.f / (1.f + __expf(-v.w));
  }
  return v;
}

template <bool PRED, bool YIN>
__device__ __forceinline__ float ldhrow(const float* __restrict__ src,
                                        int row, int hx, bool hact) {
  if (!hact) return 0.f;  // non-halo lanes: raw 0 (zero-pad semantics)
  if constexpr (!YIN) {
    if ((unsigned)row >= 512u) return 0.f;
  }
  float t = src[(size_t)row * 512 + hx];
  if constexpr (PRED) t = 1.f / (1.f + __expf(-t));
  return t;
}

__device__ __forceinline__ void push_surv(unsigned long long* lbuf,
                                          unsigned int* lcnt, uint32_t x,
                                          uint32_t p) {
  unsigned int pos = atomicAdd(lcnt, 1u);
  if (pos < LBUFSZ)
    lbuf[pos] = ((unsigned long long)(x >> 9) << 32) | (uint32_t)(~p);
}

// ---------------------------------------------------------------------------
// K1 part body: 4 rows x 256 cols (half width) of ONE map. Each wave runs
// this twice (pred part + mask part) -> perfect pred/mask load balance.
// 6 row-loads per 4 computed rows; rolling float4 regs fA..fD.
// ---------------------------------------------------------------------------
template <bool PRED, bool YIN>
__device__ __forceinline__ void part_body(
    const float* __restrict__ src, unsigned long long* __restrict__ bitmap,
    unsigned int* __restrict__ wcnts, unsigned long long* lbuf,
    unsigned int* lcnt, int m, int l, int h, int qq, uint32_t k0,
    uint32_t k1) {
  const int y0 = qq * 4;
  const int X0 = h * 256 + l * 4;
  const int hx = 256 - h;              // halo col: 256 (h=0) / 255 (h=1)
  const bool hact = h ? (l == 0) : (l == 63);
  const int lr = l & 15;

  float4 fA = ld4row<PRED, YIN>(src, y0 - 1, X0);
  float4 fB = ld4row<PRED, YIN>(src, y0 + 0, X0);
  float4 fC = ld4row<PRED, YIN>(src, y0 + 1, X0);
  float4 fD = ld4row<PRED, YIN>(src, y0 + 2, X0);
  float sA = ldhrow<PRED, YIN>(src, y0 - 1, hx, hact);
  float sB = ldhrow<PRED, YIN>(src, y0 + 0, hx, hact);
  float sC = ldhrow<PRED, YIN>(src, y0 + 1, hx, hact);
  float sD = ldhrow<PRED, YIN>(src, y0 + 2, hx, hact);

  unsigned int cnt = 0;
  unsigned long long* __restrict__ bm2 =
      bitmap + (size_t)m * NWORDS + (size_t)y0 * 8 + (h * 4 + (l >> 4));
  uint32_t pbase = (uint32_t)(y0 * 512 + X0);

#define ROWQ(RA, RB, RC, SA, SB, SC, II)                                      \
  do {                                                                        \
    float t0 = RA.x + 2.f * RB.x + RC.x, t1 = RA.y + 2.f * RB.y + RC.y;       \
    float t2 = RA.z + 2.f * RB.z + RC.z, t3 = RA.w + 2.f * RB.w + RC.w;       \
    float u0 = RC.x - RA.x, u1 = RC.y - RA.y;                                 \
    float u2 = RC.z - RA.z, u3 = RC.w - RA.w;                                 \
    float th = SA + 2.f * SB + SC, uh = SC - SA;                              \
    float tU = __shfl_up(t3, 1), uU = __shfl_up(u3, 1);                       \
    float tD = __shfl_down(t0, 1), uD = __shfl_down(u0, 1);                   \
    if (l == 0) { tU = th; uU = uh; }                                         \
    if (l == 63) { tD = th; uD = uh; }                                        \
    float ex0 = t1 - tU, ex1 = t2 - t0, ex2 = t3 - t1, ex3 = tD - t2;         \
    float ey0 = uU + 2.f * u0 + u1, ey1 = u0 + 2.f * u1 + u2;                 \
    float ey2 = u1 + 2.f * u2 + u3, ey3 = u2 + 2.f * u3 + uD;                 \
    uint32_t nib = (ex0 * ex0 + ey0 * ey0 > 0.25f ? 1u : 0u) |                \
                   (ex1 * ex1 + ey1 * ey1 > 0.25f ? 2u : 0u) |                \
                   (ex2 * ex2 + ey2 * ey2 > 0.25f ? 4u : 0u) |                \
                   (ex3 * ex3 + ey3 * ey3 > 0.25f ? 8u : 0u);                 \
    uint32_t z0, z1, z2, z3;                                                  \
    tf4(k0, k1, pbase, z0, z1, z2, z3);                                       \
    uint32_t qm = (z0 >= MT_BITS ? 1u : 0u) | (z1 >= MT_BITS ? 2u : 0u) |     \
                  (z2 >= MT_BITS ? 4u : 0u) | (z3 >= MT_BITS ? 8u : 0u);      \
    uint32_t sv = nib & qm;                                                   \
    if (sv) {                                                                 \
      if (sv & 1u) push_surv(lbuf, lcnt, z0, pbase);                          \
      if (sv & 2u) push_surv(lbuf, lcnt, z1, pbase + 1u);                     \
      if (sv & 4u) push_surv(lbuf, lcnt, z2, pbase + 2u);                     \
      if (sv & 8u) push_surv(lbuf, lcnt, z3, pbase + 3u);                     \
    }                                                                         \
    unsigned long long full = (unsigned long long)nib << (4 * lr);            \
    uint32_t wlo = (uint32_t)full, whi = (uint32_t)(full >> 32);              \
    wlo |= dpp_or0<0x111>(wlo); whi |= dpp_or0<0x111>(whi);                   \
    wlo |= dpp_or0<0x112>(wlo); whi |= dpp_or0<0x112>(whi);                   \
    wlo |= dpp_or0<0x114>(wlo); whi |= dpp_or0<0x114>(whi);                   \
    wlo |= dpp_or0<0x118>(wlo); whi |= dpp_or0<0x118>(whi);                   \
    if (lr == 15) {                                                           \
      unsigned long long word = ((unsigned long long)whi << 32) | wlo;        \
      bm2[(II) * 8] = word;                                                   \
      cnt += (unsigned int)__popcll(word);                                    \
    }                                                                         \
    pbase += 512u;                                                            \
  } while (0)

  ROWQ(fA, fB, fC, sA, sB, sC, 0);
  fA = ld4row<PRED, YIN>(src, y0 + 3, X0);
  sA = ldhrow<PRED, YIN>(src, y0 + 3, hx, hact);
  ROWQ(fB, fC, fD, sB, sC, sD, 1);
  fB = ld4row<PRED, YIN>(src, y0 + 4, X0);
  sB = ldhrow<PRED, YIN>(src, y0 + 4, hx, hact);
  ROWQ(fC, fD, fA, sC, sD, sA, 2);
  ROWQ(fD, fA, fB, sD, sA, sB, 3);
#undef ROWQ

  // unit total = sum of the 4 tail-lane partials (lanes 15/31/47/63).
  cnt += __shfl_xor(cnt, 16);
  cnt += __shfl_xor(cnt, 32);
  if (l == 15) wcnts[m * 256 + 2 * qq + h] = cnt;
}

// ---------------------------------------------------------------------------
// K1: fused Sobel+threefry+collect, pred/mask balanced. 2048 blocks (1D):
// block b -> sample s = b>>6, band j = b&63 (rows [8j, 8j+8)). Each of the
// 4 waves: h = v&1, qq = 2j + (v>>1); does 4 pred rows THEN 4 mask rows.
// Every block has identical cost -> no pred-tail.
// ---------------------------------------------------------------------------
__global__ __launch_bounds__(256) void edge_collect_kernel(
    const float* __restrict__ mo, const float* __restrict__ lb,
    unsigned long long* __restrict__ bitmap, unsigned int* __restrict__ wcnts,
    unsigned long long* __restrict__ cand, unsigned int* __restrict__ bcnt,
    float* __restrict__ out) {
  const int b = blockIdx.x;
  const int s = b >> 6;        // sample [0,32)
  const int j = b & 63;        // 8-row band [0,64)
  const int v = threadIdx.x >> 6;
  const int l = threadIdx.x & 63;
  const int h = v & 1;
  const int qq = 2 * j + (v >> 1);  // row-quad [0,128)
  const int mA = 2 * s;        // pred map (model_output)
  const int mB = 2 * s + 1;    // mask map (labels)
  const float* __restrict__ srcP = mo + (size_t)s * NPIX;
  const float* __restrict__ srcM = lb + (size_t)s * NPIX;

  if (b == 0 && threadIdx.x == 0) out[0] = 0.f;

  __shared__ unsigned long long lbufP[LBUFSZ], lbufM[LBUFSZ];
  __shared__ unsigned int lcntP, lcntM;
  if (threadIdx.x == 0) { lcntP = 0; lcntM = 0; }
  __syncthreads();

  uint32_t ka0, ka1, kb0, kb1;
  map_key(mA, ka0, ka1);
  map_key(mB, kb0, kb1);
  ka0 = (uint32_t)__builtin_amdgcn_readfirstlane((int)ka0);
  ka1 = (uint32_t)__builtin_amdgcn_readfirstlane((int)ka1);
  kb0 = (uint32_t)__builtin_amdgcn_readfirstlane((int)kb0);
  kb1 = (uint32_t)__builtin_amdgcn_readfirstlane((int)kb1);

  const bool yin = (qq != 0) && (qq != 127);
  if (yin) {
    part_body<true, true>(srcP, bitmap, wcnts, lbufP, &lcntP, mA, l, h, qq, ka0, ka1);
    part_body<false, true>(srcM, bitmap, wcnts, lbufM, &lcntM, mB, l, h, qq, kb0, kb1);
  } else {
    part_body<true, false>(srcP, bitmap, wcnts, lbufP, &lcntP, mA, l, h, qq, ka0, ka1);
    part_body<false, false>(srcM, bitmap, wcnts, lbufM, &lcntM, mB, l, h, qq, kb0, kb1);
  }

  __syncthreads();
  const unsigned int tP = lcntP, tM = lcntM;
  const unsigned int ccP = tP < SLOTS ? tP : SLOTS;
  const unsigned int ccM = tM < SLOTS ? tM : SLOTS;
  for (unsigned int i = threadIdx.x; i < ccP; i += 256)
    cand[(size_t)mA * CAP + j * SLOTS + i] = lbufP[i];
  for (unsigned int i = threadIdx.x; i < ccM; i += 256)
    cand[(size_t)mB * CAP + j * SLOTS + i] = lbufM[i];
  if (threadIdx.x == 0) {
    bcnt[mA * 64 + j] = tP;
    bcnt[mB * 64 + j] = tM;
  }
}

// block-level N = sum of the 256 per-unit counts.
__device__ __forceinline__ void reduce_N(const unsigned int* __restrict__ wcnts,
                                         int m, int tid, unsigned int* sN) {
  if (tid < 64) {
    const unsigned int* w = wcnts + m * 256;
    unsigned int v = w[tid] + w[tid + 64] + w[tid + 128] + w[tid + 192];
#pragma unroll
    for (int off = 32; off > 0; off >>= 1) v += __shfl_xor(v, off, 64);
    if (tid == 0) *sN = v;
  }
}

// ---------------------------------------------------------------------------
// K2: compact per-band slots -> radix-SELECT top-`need` set. Fallback exact
// bitmap rescan on overflow/shortfall (correctness unconditional).
// ---------------------------------------------------------------------------
__global__ __launch_bounds__(256) void select_kernel(
    const unsigned long long* __restrict__ bitmap,
    const unsigned int* __restrict__ wcnts,
    const unsigned long long* __restrict__ cand,
    const unsigned int* __restrict__ bcnt,
    uint32_t* __restrict__ pts, unsigned int* __restrict__ nsel) {
  const int m = blockIdx.x;
  const int tid = threadIdx.x;
  __shared__ unsigned long long buf[CAP];
  __shared__ unsigned int hist[256];
  __shared__ unsigned int scnt64[64];
  __shared__ unsigned int sbase[65];
  __shared__ unsigned int s_tot, s_cnt, s_b, s_rank, sN, s_ovf;

  reduce_N(wcnts, m, tid, &sN);
  if (tid < 64) scnt64[tid] = bcnt[m * 64 + tid];
  __syncthreads();
  const unsigned int N = sN;
  if (N == 0) { if (tid == 0) nsel[m] = 0; return; }
  const unsigned int need = N < NPTS ? N : NPTS;

  if (tid == 0) {
    unsigned int s = 0, ovf = 0;
    for (int i = 0; i < 64; ++i) {
      sbase[i] = s;
      unsigned int cg = scnt64[i];
      if (cg > SLOTS) ovf = 1;
      s += cg < SLOTS ? cg : SLOTS;
    }
    sbase[64] = s;
    s_ovf = ovf;
  }
  __syncthreads();

  unsigned int c;
  if (!s_ovf && sbase[64] >= need) {
    c = sbase[64];
    const int g = tid >> 2, j0 = tid & 3;  // 64 groups x 4 threads
    const unsigned int cg = scnt64[g] < SLOTS ? scnt64[g] : SLOTS;
    for (unsigned int i = j0; i < cg; i += 4)
      buf[sbase[g] + i] = cand[(size_t)m * CAP + g * SLOTS + i];
    __syncthreads();
  } else {
    // fallback: exact iterative rescan of the bitmap
    uint32_t k0, k1;
    map_key(m, k0, k1);
    const unsigned long long* __restrict__ wmap = bitmap + (size_t)m * NWORDS;
    unsigned int mt = 0, cnt = 0;
    double target = TARGET;
    for (int iter = 0; iter < 16; ++iter) {
      mt = ((double)N > target)
               ? (unsigned int)(8388608.0 * (1.0 - target / (double)N))
               : 0u;
      if (tid == 0) s_tot = 0;
      __syncthreads();
      unsigned int lc = 0;
      for (int w = tid; w < NWORDS; w += 256) {
        unsigned long long word = wmap[w];
        while (word) {
          int bpos = __builtin_ctzll(word);
          word &= word - 1;
          uint32_t p = ((uint32_t)w << 6) + (uint32_t)bpos;
          lc += (score23(k0, k1, p) >= mt) ? 1u : 0u;
        }
      }
      if (lc) atomicAdd(&s_tot, lc);
      __syncthreads();
      cnt = s_tot;
      __syncthreads();
      if (cnt >= need && cnt <= CAP) break;
      if (cnt < need) target *= 3.0; else target *= 0.5;
    }
    if (tid == 0) s_cnt = 0;
    __syncthreads();
    for (int w = tid; w < NWORDS; w += 256) {
      unsigned long long word = wmap[w];
      while (word) {
        int bpos = __builtin_ctzll(word);
        word &= word - 1;
        uint32_t p = ((uint32_t)w << 6) + (uint32_t)bpos;
        uint32_t sc = score23(k0, k1, p);
        if (sc >= mt) {
          unsigned int pos = atomicAdd(&s_cnt, 1u);
          if (pos < CAP)
            buf[pos] = ((unsigned long long)sc << 32) | (uint32_t)(~p);
        }
      }
    }
    __syncthreads();
    c = s_cnt < CAP ? s_cnt : CAP;
    __syncthreads();
  }

  unsigned long long T = 0ull;
  if (c > need) {
    unsigned int rank = need;
    unsigned long long prefix = 0ull;
    for (int sh = 48; sh >= 0; sh -= 8) {
      hist[tid] = 0;
      __syncthreads();
      for (unsigned int i = tid; i < c; i += 256) {
        unsigned long long k = buf[i];
        if ((k >> (sh + 8)) == (prefix >> (sh + 8)))
          atomicAdd(&hist[(unsigned int)(k >> sh) & 255u], 1u);
      }
      __syncthreads();
      if (tid < 64) {
        unsigned int h0 = hist[4 * tid], h1 = hist[4 * tid + 1];
        unsigned int h2 = hist[4 * tid + 2], h3 = hist[4 * tid + 3];
        unsigned int gsum = h0 + h1 + h2 + h3;
        unsigned int s = gsum;
#pragma unroll
        for (int off = 1; off < 64; off <<= 1) {
          unsigned int o = __shfl_down(s, off, 64);
          s += (tid + off < 64) ? o : 0u;
        }
        unsigned int above = s - gsum;  // strictly higher digits
        unsigned int S3 = above, S2 = S3 + h3, S1 = S2 + h2, S0 = S1 + h1;
        if (S3 < rank && rank <= S3 + h3) { s_b = 4 * tid + 3; s_rank = rank - S3; }
        if (S2 < rank && rank <= S2 + h2) { s_b = 4 * tid + 2; s_rank = rank - S2; }
        if (S1 < rank && rank <= S1 + h1) { s_b = 4 * tid + 1; s_rank = rank - S1; }
        if (S0 < rank && rank <= S0 + h0) { s_b = 4 * tid + 0; s_rank = rank - S0; }
      }
      __syncthreads();
      prefix |= ((unsigned long long)s_b) << sh;
      rank = s_rank;
    }
    T = prefix;  // exact need-th largest key
  }

  if (tid == 0) s_cnt = 0;
  __syncthreads();
  for (unsigned int i = tid; i < c; i += 256) {
    unsigned long long k = buf[i];
    if (k >= T) {
      unsigned int pos = atomicAdd(&s_cnt, 1u);
      if (pos < NPTS) {
        uint32_t p = ~(uint32_t)k;
        pts[(size_t)m * NPTS + pos] = ((p >> 9) << 16) | (p & 511u);
      }
    }
  }
  __syncthreads();
  if (tid == 0) nsel[m] = s_cnt < need ? s_cnt : need;
}

// ---------------------------------------------------------------------------
// K3: Prim MST + fused finalize (unchanged — passed absmax 0).
// ---------------------------------------------------------------------------
__global__ __launch_bounds__(128, 1) void mst_kernel(
    const uint32_t* __restrict__ pts, const unsigned int* __restrict__ nsel,
    float* __restrict__ out) {
  const int wv = threadIdx.x >> 6;  // 0 = pred, 1 = mask
  const int m = blockIdx.x * 2 + wv;
  const int l = threadIdx.x & 63;
  const int n = (int)nsel[m];
  __shared__ float stp[2];

  unsigned int utp = 0;
  if (n > 1) {
    uint32_t pk[5], key[5];
    int px[5], py[5];
#pragma unroll
    for (int k = 0; k < 5; ++k) {
      int id = k * 64 + l;
      pk[k] = (id < n) ? pts[(size_t)m * NPTS + id] : 0u;
    }
    const uint32_t p0 = (uint32_t)__builtin_amdgcn_readlane((int)pk[0], 0);
    const int x0 = (int)(p0 >> 16), y0 = (int)(p0 & 0xFFFFu);
#pragma unroll
    for (int k = 0; k < 5; ++k) {
      int id = k * 64 + l;
      px[k] = (int)(pk[k] >> 16);
      py[k] = (int)(pk[k] & 0xFFFFu);
      if (id > 0 && id < n) {
        int dx = px[k] - x0, dy = py[k] - y0;
        key[k] = ((uint32_t)(__mul24(dx, dx) + __mul24(dy, dy)) << 9) |
                 (uint32_t)id;
      } else {
        key[k] = 0xFFFFFFFFu;
      }
    }

    for (int it = 0; it < n - 1; ++it) {
      uint32_t best = umin32(umin32(umin32(key[0], key[1]),
                                    umin32(key[2], key[3])), key[4]);
      best = wave_min_u32_bcast(best);
      utp += best >> 9;  // exact: sum < 2^31
      const int j = (int)(best & 511u);
      const int ko = j >> 6, lo = j & 63;
      uint32_t cp = pk[0];
#pragma unroll
      for (int k = 1; k < 5; ++k) cp = (ko == k) ? pk[k] : cp;
      const uint32_t pj = (uint32_t)__builtin_amdgcn_readlane((int)cp, lo);
      const int jx = (int)(pj >> 16), jy = (int)(pj & 0xFFFFu);
#pragma unroll
      for (int k = 0; k < 5; ++k) {
        int dx = px[k] - jx, dy = py[k] - jy;
        uint32_t nk = ((uint32_t)(__mul24(dx, dx) + __mul24(dy, dy)) << 9) |
                      (uint32_t)(k * 64 + l);
        uint32_t upd =
            (key[k] == 0xFFFFFFFFu) ? 0xFFFFFFFFu : umin32(key[k], nk);
        key[k] = (k == ko && l == lo) ? 0xFFFFFFFFu : upd;
      }
    }
  }
  if (l == 0) stp[wv] = (float)utp;
  __syncthreads();
  if (threadIdx.x == 0)
    atomicAdd(out, 1e-5f * fabsf(stp[1] - stp[0]) / 32.f);
}

// ---------------------------------------------------------------------------
extern "C" void kernel_launch(void* const* d_in, const int* in_sizes, int n_in,
                              void* d_out, int out_size, void* d_ws,
                              size_t ws_size, hipStream_t stream) {
  const float* mo = (const float*)d_in[0];
  const float* lb = (const float*)d_in[1];
  float* out = (float*)d_out;
  char* ws = (char*)d_ws;

  // ws layout (~3.30 MB):
  unsigned long long* bitmap = (unsigned long long*)ws;            // 2 MB
  unsigned long long* cand = (unsigned long long*)(ws + 2097152);  // 1 MB
  unsigned int* wcnts = (unsigned int*)(ws + 3145728);             // 64 KB
  unsigned int* bcnt  = (unsigned int*)(ws + 3211264);             // 16 KB
  unsigned int* nsel  = (unsigned int*)(ws + 3227648);             // 256 B
  uint32_t* pts       = (uint32_t*)(ws + 3227904);                 // 75 KB

  edge_collect_kernel<<<2048, 256, 0, stream>>>(mo, lb, bitmap, wcnts,
                                                cand, bcnt, out);
  select_kernel<<<NMAPS, 256, 0, stream>>>(bitmap, wcnts, cand, bcnt, pts,
                                           nsel);
  mst_kernel<<<32, 128, 0, stream>>>(pts, nsel, out);
}